// Round 5
// baseline (198.216 us; speedup 1.0000x reference)
//
#include <hip/hip_runtime.h>

#define HDIM  256
#define YP    264              // padded Y row length in bf16 elems (same-row b128 reads stay 16B-aligned)
#define SPBM  8                // samples per block
#define MROWS (SPBM * 8)       // 64 jet rows per block
// channel-row order within a sample (rows 8s..8s+7):
//   [0]=v  [1]=g0  [2]=s0  [3]=g3  |  [4]=g1  [5]=s1  [6]=g2  [7]=s2
// lo-quarter lanes hold rows 0-3, hi-quarter rows 4-7 -> partner = lane^16, 1 shfl/tile.

typedef unsigned short u16;
typedef __attribute__((ext_vector_type(8))) short  short8;   // 8 bf16 (4 VGPRs)
typedef __attribute__((ext_vector_type(4))) float  f32x4;    // MFMA acc

__device__ __forceinline__ float bf2f(u16 u) {
    union { unsigned int i; float f; } v; v.i = ((unsigned int)u) << 16; return v.f;
}
__device__ __forceinline__ u16 f2bf(float f) {
    union { float f; unsigned int u; } v; v.f = f;
    return (u16)((v.u + 0x8000u) >> 16);
}
__device__ __forceinline__ unsigned int pack2bf(float a, float b) {
    union { float f; unsigned int u; } va, vb; va.f = a; vb.f = b;
    return ((va.u + 0x8000u) >> 16) | (((vb.u + 0x8000u) >> 16) << 16);
}
__device__ __forceinline__ u16 f2bf_rne(float f) {
    union { float f; unsigned int u; } v; v.f = f;
    unsigned int r = v.u + 0x7fffu + ((v.u >> 16) & 1u);
    return (u16)(r >> 16);
}
// tanh(x) = 1 - 2/(e^{2x}+1) on raw v_exp_f32 / v_rcp_f32
__device__ __forceinline__ float fast_tanh(float x) {
    const float e = __builtin_amdgcn_exp2f(x * 2.885390081777927f);
    const float r = __builtin_amdgcn_rcpf(e + 1.f);
    return 1.f - 2.f * r;
}

// ---- prepass: LDS-tiled transpose W[k][n] f32 -> Wt[n][k] bf16 (W1,W2,W3),
// ---- plus Wo[k][2] -> Wob[2][256] bf16 at ws + 3*65536.
__global__ __launch_bounds__(256)
void prep_w(const float* __restrict__ W1, const float* __restrict__ W2,
            const float* __restrict__ W3, const float* __restrict__ Wo,
            u16* __restrict__ ws) {
    const int bid = blockIdx.x;
    const int tid = threadIdx.x;
    if (bid == 48) {
#pragma unroll
        for (int oc = 0; oc < 2; ++oc)
            ws[3 * 65536 + oc * 256 + tid] = f2bf_rne(Wo[tid * 2 + oc]);
        return;
    }
    const int which = bid >> 4;
    const int tile  = bid & 15;
    const int k0 = (tile >> 2) * 64, n0 = (tile & 3) * 64;
    const float* W = (which == 0) ? W1 : ((which == 1) ? W2 : W3);
    __shared__ float T[64][65];
    const int rk = tid >> 4;
    const int rn = (tid & 15) * 4;
#pragma unroll
    for (int rep = 0; rep < 4; ++rep) {
        const float4 v = *(const float4*)(W + (k0 + rep * 16 + rk) * 256 + n0 + rn);
        T[rep * 16 + rk][rn + 0] = v.x;
        T[rep * 16 + rk][rn + 1] = v.y;
        T[rep * 16 + rk][rn + 2] = v.z;
        T[rep * 16 + rk][rn + 3] = v.w;
    }
    __syncthreads();
    const int wn = tid >> 4;
    const int wk = (tid & 15) * 4;
#pragma unroll
    for (int rep = 0; rep < 4; ++rep) {
        const int nl = rep * 16 + wn;
        ushort4 o;
        o.x = f2bf_rne(T[wk + 0][nl]);
        o.y = f2bf_rne(T[wk + 1][nl]);
        o.z = f2bf_rne(T[wk + 2][nl]);
        o.w = f2bf_rne(T[wk + 3][nl]);
        *(ushort4*)(ws + which * 65536 + (n0 + nl) * 256 + k0 + wk) = o;
    }
}

// ---- one hidden layer: Y(LDS, 64x256 bf16 jets) @ W(256x256), 2 waves x 128 cols ----
// C/D: col=lane&15, row=(lane>>4)*4+reg.  A: A[m=lane&15][k=8*(lane>>4)+j].
__device__ __forceinline__ void hidden_layer_mfma(u16* __restrict__ Y,
                                                  const u16* __restrict__ Wt,
                                                  const float* __restrict__ b,
                                                  int l, int wv) {
    const int lm    = l & 15;
    const int lk8   = (l >> 4) * 8;
    const int nbase = wv * 128;

    f32x4 acc[4][8];
#pragma unroll
    for (int mt = 0; mt < 4; ++mt)
#pragma unroll
        for (int nt = 0; nt < 8; ++nt) acc[mt][nt] = (f32x4){0.f, 0.f, 0.f, 0.f};

#pragma unroll
    for (int ks = 0; ks < 8; ++ks) {
        const int kk = ks * 32 + lk8;
        short8 a[4], bf[8];
#pragma unroll
        for (int mt = 0; mt < 4; ++mt)
            a[mt] = *(const short8*)(Y + (mt * 16 + lm) * YP + kk);
#pragma unroll
        for (int nt = 0; nt < 8; ++nt)
            bf[nt] = *(const short8*)(Wt + ((nbase + nt * 16 + lm) << 8) + kk);
#pragma unroll
        for (int mt = 0; mt < 4; ++mt)
#pragma unroll
            for (int nt = 0; nt < 8; ++nt)
                acc[mt][nt] = __builtin_amdgcn_mfma_f32_16x16x32_bf16(
                    a[mt], bf[nt], acc[mt][nt], 0, 0, 0);
    }

    float bias[8];
#pragma unroll
    for (int nt = 0; nt < 8; ++nt) bias[nt] = b[nbase + nt * 16 + lm];

    __syncthreads();   // all waves done READING Y before anyone overwrites it

    const int hi = (l >> 4) & 1;  // 0: rows [v,g0,s0,g3]  1: rows [g1,s1,g2,s2]
#pragma unroll
    for (int mt = 0; mt < 4; ++mt) {
        const int r0 = mt * 16 + (l >> 4) * 4;
#pragma unroll
        for (int nt = 0; nt < 8; ++nt) {
            const f32x4 u = acc[mt][nt];
            const float ty  = fast_tanh(u[0] + bias[nt]);  // valid on lo lanes
            const float typ = __shfl_xor(ty, 16);          // the ONE cross-lane op
            const float tv = hi ? typ : ty;
            const float t  = 1.f - tv * tv;
            const float mc = -2.f * tv * t;
            // lo: o=[ty, t*g0, t*s0+mc*g0^2, t*g3]  hi: o=[t*g1, t*s1+mc*g1^2, t*g2, t*s2+mc*g2^2]
            const float o0 = hi ? t * u[0] : ty;
            const float o1 = t * u[1] + (hi ? mc * u[0] * u[0] : 0.f);
            const float o2 = t * u[2] + (hi ? 0.f : mc * u[1] * u[1]);
            const float o3 = t * u[3] + (hi ? mc * u[2] * u[2] : 0.f);
            const int n = nbase + nt * 16 + lm;
            Y[(r0 + 0) * YP + n] = f2bf(o0);
            Y[(r0 + 1) * YP + n] = f2bf(o1);
            Y[(r0 + 2) * YP + n] = f2bf(o2);
            Y[(r0 + 3) * YP + n] = f2bf(o3);
        }
    }
    __syncthreads();
}

__global__ __launch_bounds__(128, 2)
void mlp_jet_mfma(const float* __restrict__ x,
                  const float* __restrict__ W0, const float* __restrict__ b0,
                  const float* __restrict__ b1, const float* __restrict__ b2,
                  const float* __restrict__ b3, const float* __restrict__ bo,
                  const u16* __restrict__ Wt,   // 3 x Wt[n][k] bf16, + Wob[2][256]
                  float* __restrict__ out, int nB) {
    __shared__ __align__(16) u16 Y[MROWS * YP];
    __shared__ float4 xs4[SPBM];
    __shared__ float  part[MROWS][2];

    const int tid = threadIdx.x;
    const int wv  = tid >> 6;
    const int l   = tid & 63;
    const int lm  = l & 15;
    const int lk8 = (l >> 4) * 8;
    const int n0  = blockIdx.x * SPBM;

    // ---- layer 0: 4 -> 256, VALU; thread owns neurons 2*tid, 2*tid+1 ----
    if (tid < SPBM) xs4[tid] = *(const float4*)(x + (n0 + tid) * 4);
    __syncthreads();
    {
        const int n2 = tid * 2;
        const float2 w0p = *(const float2*)(W0 + 0 * HDIM + n2);
        const float2 w1p = *(const float2*)(W0 + 1 * HDIM + n2);
        const float2 w2p = *(const float2*)(W0 + 2 * HDIM + n2);
        const float2 w3p = *(const float2*)(W0 + 3 * HDIM + n2);
        const float2 bbp = *(const float2*)(b0 + n2);
#pragma unroll
        for (int s = 0; s < SPBM; ++s) {
            const float4 xv = xs4[s];
            const float uA = xv.x * w0p.x + xv.y * w1p.x + xv.z * w2p.x + xv.w * w3p.x + bbp.x;
            const float uB = xv.x * w0p.y + xv.y * w1p.y + xv.z * w2p.y + xv.w * w3p.y + bbp.y;
            const float tyA = fast_tanh(uA), tyB = fast_tanh(uB);
            const float tA = 1.f - tyA * tyA, tB = 1.f - tyB * tyB;
            const float mA = -2.f * tyA * tA, mB = -2.f * tyB * tB;
            unsigned int* yr = (unsigned int*)(Y + (8 * s) * YP + n2);
            const int st = YP / 2;   // u32 stride per row
            yr[0 * st] = pack2bf(tyA, tyB);                          // v
            yr[1 * st] = pack2bf(tA * w0p.x, tB * w0p.y);            // g0
            yr[2 * st] = pack2bf(mA * w0p.x * w0p.x, mB * w0p.y * w0p.y); // s0
            yr[3 * st] = pack2bf(tA * w3p.x, tB * w3p.y);            // g3
            yr[4 * st] = pack2bf(tA * w1p.x, tB * w1p.y);            // g1
            yr[5 * st] = pack2bf(mA * w1p.x * w1p.x, mB * w1p.y * w1p.y); // s1
            yr[6 * st] = pack2bf(tA * w2p.x, tB * w2p.y);            // g2
            yr[7 * st] = pack2bf(mA * w2p.x * w2p.x, mB * w2p.y * w2p.y); // s2
        }
    }
    __syncthreads();

    // ---- 3 hidden layers on the matrix pipe ----
    hidden_layer_mfma(Y, Wt + 0 * 65536, b1, l, wv);
    hidden_layer_mfma(Y, Wt + 1 * 65536, b2, l, wv);
    hidden_layer_mfma(Y, Wt + 2 * 65536, b3, l, wv);

    // ---- output head on MFMA: wave wv takes rows wv*32..wv*32+31 (2 tiles) ----
    {
        const u16* wob = Wt + 3 * 65536;
#pragma unroll
        for (int mh = 0; mh < 2; ++mh) {
            f32x4 h = (f32x4){0.f, 0.f, 0.f, 0.f};
#pragma unroll
            for (int ks = 0; ks < 8; ++ks) {
                const int kk = ks * 32 + lk8;
                const short8 a = *(const short8*)(Y + (wv * 32 + mh * 16 + lm) * YP + kk);
                short8 bfr = (short8){0,0,0,0,0,0,0,0};
                if (lm < 2) bfr = *(const short8*)(wob + lm * 256 + kk);
                h = __builtin_amdgcn_mfma_f32_16x16x32_bf16(a, bfr, h, 0, 0, 0);
            }
            if (lm < 2) {
#pragma unroll
                for (int r = 0; r < 4; ++r)
                    part[wv * 32 + mh * 16 + (l >> 4) * 4 + r][lm] = h[r];
            }
        }
    }
    __syncthreads();

    if (tid < SPBM) {
        const int s = tid;
        float q0[8], q1[8];
#pragma unroll
        for (int ch = 0; ch < 8; ++ch) {
            q0[ch] = part[8 * s + ch][0];
            q1[ch] = part[8 * s + ch][1];
        }
        // permuted rows: [0]=v [1]=g0 [2]=s0 [3]=g3 [4]=g1 [5]=s1 [6]=g2 [7]=s2
        const float c0  = q0[0] + bo[0];
        const float Fi  = q1[0] + bo[1];
        const float cg0 = q0[1], cg1 = q0[4], cg2 = q0[6];
        const float ct  = q0[3];                 // dc/dx_3 (TDIM)
        const float fg0 = q1[1], fg1 = q1[4], fg2 = q1[6];
        const float trHc  = q0[2] + q0[5] + q0[7];
        const float fiLap = q1[2] + q1[5] + q1[7];
        const float jd = -trHc
                         - (cg0 * fg0 + cg1 * fg1 + cg2 * fg2 + c0 * fiLap)
                         + 0.1f * (cg0 + cg1 + cg2);
        const int n = n0 + s;
        out[0 * nB + n]         = c0;
        out[1 * nB + n]         = ct;
        out[2 * nB + 3 * n + 0] = cg0;
        out[2 * nB + 3 * n + 1] = cg1;
        out[2 * nB + 3 * n + 2] = cg2;
        out[5 * nB + n]         = Fi;
        out[6 * nB + 3 * n + 0] = fg0;
        out[6 * nB + 3 * n + 1] = fg1;
        out[6 * nB + 3 * n + 2] = fg2;
        out[9 * nB + n]         = fiLap;
        out[10 * nB + n]        = jd;
    }
}

extern "C" void kernel_launch(void* const* d_in, const int* in_sizes, int n_in,
                              void* d_out, int out_size, void* d_ws, size_t ws_size,
                              hipStream_t stream) {
    const float* x  = (const float*)d_in[0];
    const float* W0 = (const float*)d_in[1];
    const float* b0 = (const float*)d_in[2];
    const float* W1 = (const float*)d_in[3];
    const float* b1 = (const float*)d_in[4];
    const float* W2 = (const float*)d_in[5];
    const float* b2 = (const float*)d_in[6];
    const float* W3 = (const float*)d_in[7];
    const float* b3 = (const float*)d_in[8];
    const float* Wo = (const float*)d_in[9];
    const float* bo = (const float*)d_in[10];
    float* out = (float*)d_out;
    u16*   Wt  = (u16*)d_ws;                 // 3*65536 + 512 bf16 ≈ 385 KB

    const int nB = in_sizes[0] / 4;          // 16384

    hipLaunchKernelGGL(prep_w, dim3(49), dim3(256), 0, stream, W1, W2, W3, Wo, Wt);
    hipLaunchKernelGGL(mlp_jet_mfma, dim3(nB / SPBM), dim3(128), 0, stream,
                       x, W0, b0, b1, b2, b3, bo, Wt, out, nB);
}